// Round 4
// baseline (451.008 us; speedup 1.0000x reference)
//
#include <hip/hip_runtime.h>
#include <math.h>

// PPO fused loss, round 4: transposed-GEMM main kernel, zero K-loop barriers.
//   h^T = tanh(W1^T (x) states^T) computed per wave (K-split over H);
//   C1 layout -> GEMM2 B-operand via ds_bpermute (no LDS round-trip);
//   heads accumulate per wave, one block barrier for cross-wave K-reduce.
// Aux: prep (weight bf16 fragments) fused with scan1 into one launch.
// 5 kernels: prep_scan1, scan2, scan3, main3, finalize.

typedef __attribute__((ext_vector_type(8))) short short8_t;
typedef __attribute__((ext_vector_type(4))) float float4_t;

#define T_TOTAL 262144
#define S_DIM 128
#define H_DIM 1024
#define A_DIM 16
#define GAMMA 0.99f

#define SEG 32
#define NSEG 8192
#define SCAN_BLOCKS 32

// ws float offsets
#define WS_SUM   0
#define WS_SUMSQ 1
#define WS_MEAN  2
#define WS_ISTD  3
#define WS_TERM  4
#define WS_CTR   5
#define WS_SEGA  8
#define WS_SEGB  (WS_SEGA + NSEG)
#define WS_INC   (WS_SEGB + NSEG)
#define WS_ADV   (WS_INC + NSEG)           // + T floats
#define WS_W1F   (WS_ADV + T_TOTAL)        // 131072 bf16
#define WS_WHF   (WS_W1F + 65536)          // 32768 bf16

__device__ __forceinline__ unsigned pkbf(float a, float b) {
  unsigned r;
  asm("v_cvt_pk_bf16_f32 %0, %1, %2" : "=v"(r) : "v"(a), "v"(b));
  return r;
}

__device__ __forceinline__ float fast_tanh(float x) {
  float e = __builtin_amdgcn_exp2f(x * 2.8853900817779268f);
  return fmaf(-2.0f, __builtin_amdgcn_rcpf(e + 1.0f), 1.0f);
}

// ---------------- prep + scan1 fused ----------------
// blocks [0,64)  : W1 -> bf16 frags [nt(64)][kf(4)][lane(64)][e(8)]
//                  elem = W1[kf*32+(lane>>4)*8+e][nt*16+(lane&15)]
// blocks [64,80) : W_mu|W_lv -> [nt(2)][kf(32)][lane(64)][e(8)]
// blocks [80,112): segmented scan pass 1 (SEG=32, coalesced via padded LDS)
__global__ void prep_scan1(const float* __restrict__ W1,
                           const float* __restrict__ W_mu,
                           const float* __restrict__ W_lv,
                           const float* __restrict__ rewards,
                           const int* __restrict__ masks,
                           short* __restrict__ w1f, short* __restrict__ whf,
                           float* __restrict__ ws) {
  __shared__ float lr[8448], lg[8448];
  const int bid = blockIdx.x, tid = threadIdx.x;
  if (bid < 64) {
    int id = bid * 256 + tid;
    int lane = id & 63, kf = (id >> 6) & 3, nt = id >> 8;
    int quad = lane >> 4, col = nt * 16 + (lane & 15);
    int kbase = kf * 32 + quad * 8;
#pragma unroll
    for (int e = 0; e < 8; e += 2) {
      unsigned p = pkbf(W1[(size_t)(kbase + e) * H_DIM + col],
                        W1[(size_t)(kbase + e + 1) * H_DIM + col]);
      *(unsigned*)(w1f + (size_t)id * 8 + e) = p;
    }
  } else if (bid < 80) {
    if (bid == 64 && tid < 16) ws[tid] = 0.0f;
    int id = (bid - 64) * 256 + tid;
    int lane = id & 63, kf = (id >> 6) & 31, nt = id >> 11;
    const float* src = nt ? W_lv : W_mu;
    int quad = lane >> 4, col = lane & 15;
    int kbase = kf * 32 + quad * 8;
#pragma unroll
    for (int e = 0; e < 8; e += 2) {
      unsigned p = pkbf(src[(size_t)(kbase + e) * A_DIM + col],
                        src[(size_t)(kbase + e + 1) * A_DIM + col]);
      *(unsigned*)(whf + (size_t)id * 8 + e) = p;
    }
  } else {
    const int sb = bid - 80;
    const size_t base = (size_t)sb * 8192;
    const float4* r4 = (const float4*)(rewards + base);
    const int4* m4 = (const int4*)(masks + base);
#pragma unroll
    for (int i = 0; i < 8; ++i) {
      int idx4 = tid + i * 256;
      float4 rv = r4[idx4];
      int4 mv = m4[idx4];
      int j0 = idx4 * 4, p = j0 + (j0 >> 5);
      lr[p] = rv.x; lr[p + 1] = rv.y; lr[p + 2] = rv.z; lr[p + 3] = rv.w;
      lg[p] = GAMMA * (float)mv.x; lg[p + 1] = GAMMA * (float)mv.y;
      lg[p + 2] = GAMMA * (float)mv.z; lg[p + 3] = GAMMA * (float)mv.w;
    }
    __syncthreads();
    const float* pr = lr + 33 * tid;
    const float* pg = lg + 33 * tid;
    float a = 1.0f, b = 0.0f;
#pragma unroll
    for (int i = SEG - 1; i >= 0; --i) {
      float gi = pg[i];
      b = pr[i] + gi * b;
      a *= gi;
    }
    int g = sb * 256 + tid;
    ws[WS_SEGA + g] = a;
    ws[WS_SEGB + g] = b;
  }
}

// ---------------- scan pass 2 ----------------
__global__ void scan2(float* __restrict__ ws) {
  __shared__ float lA[8448], lB[8448];
  __shared__ float gA[256], gB[256], ginc[256];
  const int tid = threadIdx.x;
  const float4* a4 = (const float4*)(ws + WS_SEGA);
  const float4* b4 = (const float4*)(ws + WS_SEGB);
#pragma unroll
  for (int i = 0; i < 8; ++i) {
    int idx4 = tid + i * 256;
    float4 av = a4[idx4], bv = b4[idx4];
    int j0 = idx4 * 4, p = j0 + (j0 >> 5);
    lA[p] = av.x; lA[p + 1] = av.y; lA[p + 2] = av.z; lA[p + 3] = av.w;
    lB[p] = bv.x; lB[p + 1] = bv.y; lB[p + 2] = bv.z; lB[p + 3] = bv.w;
  }
  __syncthreads();
  {
    const float* pA = lA + 33 * tid;
    const float* pB = lB + 33 * tid;
    float A = 1.0f, B = 0.0f;
#pragma unroll
    for (int i = 31; i >= 0; --i) {
      float as = pA[i], bs = pB[i];
      B = bs + as * B;
      A = as * A;
    }
    gA[tid] = A; gB[tid] = B;
  }
  __syncthreads();
  if (tid == 0) {
    float x = 0.0f;
    for (int g = 255; g >= 0; --g) {
      ginc[g] = x;
      x = gB[g] + gA[g] * x;
    }
  }
  __syncthreads();
  {
    float x = ginc[tid];
    float* pA = lA + 33 * tid;
    const float* pB = lB + 33 * tid;
#pragma unroll
    for (int i = 31; i >= 0; --i) {
      float as = pA[i], bs = pB[i];
      pA[i] = x;
      x = bs + as * x;
    }
  }
  __syncthreads();
  float4* o4 = (float4*)(ws + WS_INC);
#pragma unroll
  for (int i = 0; i < 8; ++i) {
    int idx4 = tid + i * 256;
    int j0 = idx4 * 4, p = j0 + (j0 >> 5);
    o4[idx4] = make_float4(lA[p], lA[p + 1], lA[p + 2], lA[p + 3]);
  }
}

// ---------------- scan pass 3 + stats ----------------
__global__ void scan3(const float* __restrict__ rewards,
                      const int* __restrict__ masks,
                      const float* __restrict__ values,
                      float* __restrict__ ws) {
  __shared__ float lr[8448], lg[8448], lv[8448];
  const int tid = threadIdx.x;
  const size_t base = (size_t)blockIdx.x * 8192;
  const float4* r4 = (const float4*)(rewards + base);
  const int4* m4 = (const int4*)(masks + base);
  const float4* v4 = (const float4*)(values + base);
#pragma unroll
  for (int i = 0; i < 8; ++i) {
    int idx4 = tid + i * 256;
    float4 rv = r4[idx4];
    int4 mv = m4[idx4];
    float4 vv = v4[idx4];
    int j0 = idx4 * 4, p = j0 + (j0 >> 5);
    lr[p] = rv.x; lr[p + 1] = rv.y; lr[p + 2] = rv.z; lr[p + 3] = rv.w;
    lg[p] = GAMMA * (float)mv.x; lg[p + 1] = GAMMA * (float)mv.y;
    lg[p + 2] = GAMMA * (float)mv.z; lg[p + 3] = GAMMA * (float)mv.w;
    lv[p] = vv.x; lv[p + 1] = vv.y; lv[p + 2] = vv.z; lv[p + 3] = vv.w;
  }
  __syncthreads();
  float* pr = lr + 33 * tid;
  const float* pg = lg + 33 * tid;
  const float* pv = lv + 33 * tid;
  float x = ws[WS_INC + blockIdx.x * 256 + tid];
  float s1 = 0.0f, s2 = 0.0f;
#pragma unroll
  for (int i = SEG - 1; i >= 0; --i) {
    x = pr[i] + pg[i] * x;
    float adv = x - pv[i];
    pr[i] = adv;
    s1 += adv;
    s2 += adv * adv;
  }
#pragma unroll
  for (int m = 1; m < 64; m <<= 1) {
    s1 += __shfl_xor(s1, m);
    s2 += __shfl_xor(s2, m);
  }
  if ((tid & 63) == 0) {
    atomicAdd(&ws[WS_SUM], s1);
    atomicAdd(&ws[WS_SUMSQ], s2);
  }
  __syncthreads();
  float4* o4 = (float4*)(ws + WS_ADV + base);
#pragma unroll
  for (int i = 0; i < 8; ++i) {
    int idx4 = tid + i * 256;
    int j0 = idx4 * 4, p = j0 + (j0 >> 5);
    o4[idx4] = make_float4(lr[p], lr[p + 1], lr[p + 2], lr[p + 3]);
  }
  __threadfence();
  if (tid == 0) {
    int old = __hip_atomic_fetch_add((int*)ws + WS_CTR, 1,
                                     __ATOMIC_ACQ_REL, __HIP_MEMORY_SCOPE_AGENT);
    if (old == SCAN_BLOCKS - 1) {
      __threadfence();
      float t1 = __hip_atomic_load(&ws[WS_SUM], __ATOMIC_RELAXED, __HIP_MEMORY_SCOPE_AGENT);
      float t2 = __hip_atomic_load(&ws[WS_SUMSQ], __ATOMIC_RELAXED, __HIP_MEMORY_SCOPE_AGENT);
      float n = (float)T_TOTAL;
      float mean = t1 / n;
      float var = (t2 - t1 * t1 / n) / (n - 1.0f);
      var = fmaxf(var, 0.0f);
      ws[WS_MEAN] = mean;
      ws[WS_ISTD] = 1.0f / (sqrtf(var) + 1e-7f);
    }
  }
}

// ---------------- main kernel, transposed GEMMs ----------------
// 64 T-rows per block, 4 waves. Wave w: hcols [256w, 256(w+1)) for all 64
// rows (K-split of GEMM2). states^T loaded as B-frags straight from global.
// C1 (h^T) -> GEMM2 B-operand via ds_bpermute; no K-loop LDS or barriers.
__launch_bounds__(256, 2)
__global__ void main3(const float* __restrict__ states,
                      const float* __restrict__ actions,
                      const float* __restrict__ beta,
                      const float* __restrict__ b1g,
                      const float* __restrict__ bmug,
                      const float* __restrict__ blvg,
                      const short* __restrict__ W1f,
                      const short* __restrict__ Whf,
                      float* __restrict__ ws) {
  __shared__ float red[4 * 8 * 64 * 4];   // 32 KB: [srcw][mt*2+head][lane][4]

  const int tid = threadIdx.x;
  const int lane = tid & 63;
  const int w = tid >> 6;
  const int q = lane >> 4;
  const int m = lane & 15;
  const int t0 = blockIdx.x * 64;

  // states^T B-fragments: bs[mt][kf], lane (q,m) holds
  // states[t0+mt*16+m][kf*32+q*8 .. +8) packed bf16.
  short8_t bs[4][4];
#pragma unroll
  for (int mt = 0; mt < 4; ++mt) {
    const float* rowp = states + (size_t)(t0 + mt * 16 + m) * S_DIM + q * 8;
#pragma unroll
    for (int kf = 0; kf < 4; ++kf) {
      float4 v0 = *(const float4*)(rowp + kf * 32);
      float4 v1 = *(const float4*)(rowp + kf * 32 + 4);
      union { unsigned u[4]; short8_t s; } pk;
      pk.u[0] = pkbf(v0.x, v0.y);
      pk.u[1] = pkbf(v0.z, v0.w);
      pk.u[2] = pkbf(v1.x, v1.y);
      pk.u[3] = pkbf(v1.z, v1.w);
      bs[mt][kf] = pk.s;
    }
  }

  float4_t acc2[4][2];
#pragma unroll
  for (int mt = 0; mt < 4; ++mt) {
    acc2[mt][0] = (float4_t){0.f, 0.f, 0.f, 0.f};
    acc2[mt][1] = (float4_t){0.f, 0.f, 0.f, 0.f};
  }

  const bool hi = (lane >= 32);
  const int idxA = ((q & 1) * 32 + m) * 4;   // bpermute byte index
  const int idxB = idxA + 64;

  for (int kk = 0; kk < 8; ++kk) {
    unsigned p0[2][4], p1[2][4];
#pragma unroll
    for (int c = 0; c < 2; ++c) {
      const int nt1 = w * 16 + kk * 2 + c;
      const short8_t* ap = (const short8_t*)W1f + nt1 * 256 + lane;
      short8_t a0 = ap[0], a1 = ap[64], a2 = ap[128], a3 = ap[192];
      float4 b1v = *(const float4*)(b1g + nt1 * 16 + q * 4);
#pragma unroll
      for (int mt = 0; mt < 4; ++mt) {
        float4_t cc = (float4_t){0.f, 0.f, 0.f, 0.f};
        cc = __builtin_amdgcn_mfma_f32_16x16x32_bf16(a0, bs[mt][0], cc, 0, 0, 0);
        cc = __builtin_amdgcn_mfma_f32_16x16x32_bf16(a1, bs[mt][1], cc, 0, 0, 0);
        cc = __builtin_amdgcn_mfma_f32_16x16x32_bf16(a2, bs[mt][2], cc, 0, 0, 0);
        cc = __builtin_amdgcn_mfma_f32_16x16x32_bf16(a3, bs[mt][3], cc, 0, 0, 0);
        float h0 = fast_tanh(cc[0] + b1v.x);
        float h1 = fast_tanh(cc[1] + b1v.y);
        float h2 = fast_tanh(cc[2] + b1v.z);
        float h3 = fast_tanh(cc[3] + b1v.w);
        p0[c][mt] = pkbf(h0, h1);
        p1[c][mt] = pkbf(h2, h3);
      }
    }
    // GEMM2 over this 32-hcol group
    const int kf2 = w * 8 + kk;
    const short8_t* wp = (const short8_t*)Whf + kf2 * 64 + lane;
    short8_t amu = wp[0];
    short8_t alv = wp[32 * 64];
#pragma unroll
    for (int mt = 0; mt < 4; ++mt) {
      int v00 = __builtin_amdgcn_ds_bpermute(idxA, (int)p0[0][mt]);
      int v01 = __builtin_amdgcn_ds_bpermute(idxA, (int)p0[1][mt]);
      int v10 = __builtin_amdgcn_ds_bpermute(idxA, (int)p1[0][mt]);
      int v11 = __builtin_amdgcn_ds_bpermute(idxA, (int)p1[1][mt]);
      int v20 = __builtin_amdgcn_ds_bpermute(idxB, (int)p0[0][mt]);
      int v21 = __builtin_amdgcn_ds_bpermute(idxB, (int)p0[1][mt]);
      int v30 = __builtin_amdgcn_ds_bpermute(idxB, (int)p1[0][mt]);
      int v31 = __builtin_amdgcn_ds_bpermute(idxB, (int)p1[1][mt]);
      union { int u[4]; short8_t s; } bb;
      bb.u[0] = hi ? v01 : v00;
      bb.u[1] = hi ? v11 : v10;
      bb.u[2] = hi ? v21 : v20;
      bb.u[3] = hi ? v31 : v30;
      acc2[mt][0] = __builtin_amdgcn_mfma_f32_16x16x32_bf16(amu, bb.s, acc2[mt][0], 0, 0, 0);
      acc2[mt][1] = __builtin_amdgcn_mfma_f32_16x16x32_bf16(alv, bb.s, acc2[mt][1], 0, 0, 0);
    }
  }

  // ---- cross-wave K-reduce (single block barrier) ----
#pragma unroll
  for (int mt = 0; mt < 4; ++mt) {
    *(float4_t*)&red[((w * 8 + mt * 2 + 0) * 64 + lane) * 4] = acc2[mt][0];
    *(float4_t*)&red[((w * 8 + mt * 2 + 1) * 64 + lane) * 4] = acc2[mt][1];
  }
  __syncthreads();

  // wave w takes m-tile w: lane (q,m) owns T-row t0+w*16+m, actions 4q..4q+3
  float4_t mu4 = (float4_t){0.f, 0.f, 0.f, 0.f};
  float4_t lv4 = (float4_t){0.f, 0.f, 0.f, 0.f};
#pragma unroll
  for (int src = 0; src < 4; ++src) {
    mu4 += *(const float4_t*)&red[((src * 8 + w * 2 + 0) * 64 + lane) * 4];
    lv4 += *(const float4_t*)&red[((src * 8 + w * 2 + 1) * 64 + lane) * 4];
  }
  const int t = t0 + w * 16 + m;
  float4 bm = *(const float4*)(bmug + q * 4);
  float4 bl = *(const float4*)(blvg + q * 4);
  float4 av = *(const float4*)(actions + (size_t)t * A_DIM + q * 4);
  float4 bv = *(const float4*)(beta + (size_t)t * A_DIM + q * 4);
  float d = 0.0f;
#pragma unroll
  for (int r = 0; r < 4; ++r) {
    float mu = mu4[r] + ((const float*)&bm)[r];
    float lv = lv4[r] + ((const float*)&bl)[r];
    float isd = __builtin_amdgcn_exp2f(lv * -0.72134752044448170f);  // exp(-lv/2)
    float z = (((const float*)&av)[r] - mu) * isd;
    d += fmaf(-0.5f, z * z, fmaf(-0.5f, lv, -0.9189385332046727f)) - ((const float*)&bv)[r];
  }
  d += __shfl_xor(d, 16);
  d += __shfl_xor(d, 32);      // all lanes now hold full action-sum for row m
  float ratio = __expf(d);
  float ah = (ws[WS_ADV + t] - ws[WS_MEAN]) * ws[WS_ISTD];
  float rc = fminf(fmaxf(ratio, 0.8f), 1.2f);
  float term = fminf(ratio * ah, rc * ah);
  term += __shfl_xor(term, 1);
  term += __shfl_xor(term, 2);
  term += __shfl_xor(term, 4);
  term += __shfl_xor(term, 8);   // lane 0 of each 16-group: sum over its 16 rows
  if (lane == 0) atomicAdd(&ws[WS_TERM], term);
}

__global__ void finalize(const float* __restrict__ ws, float* __restrict__ out) {
  if (threadIdx.x == 0) {
    float n = (float)T_TOTAL;
    out[0] = ws[WS_SUMSQ] / n - ws[WS_TERM] / n;
  }
}

extern "C" void kernel_launch(void* const* d_in, const int* in_sizes, int n_in,
                              void* d_out, int out_size, void* d_ws, size_t ws_size,
                              hipStream_t stream) {
  const float* states  = (const float*)d_in[0];
  const float* actions = (const float*)d_in[1];
  const float* rewards = (const float*)d_in[2];
  const float* values  = (const float*)d_in[3];
  const float* beta    = (const float*)d_in[4];
  const float* W1      = (const float*)d_in[5];
  const float* b1      = (const float*)d_in[6];
  const float* W_mu    = (const float*)d_in[7];
  const float* b_mu    = (const float*)d_in[8];
  const float* W_lv    = (const float*)d_in[9];
  const float* b_lv    = (const float*)d_in[10];
  const int*   masks   = (const int*)d_in[11];
  float* ws = (float*)d_ws;
  float* out = (float*)d_out;
  short* w1f = (short*)(ws + WS_W1F);
  short* whf = (short*)(ws + WS_WHF);

  hipLaunchKernelGGL(prep_scan1, dim3(112), dim3(256), 0, stream,
                     W1, W_mu, W_lv, rewards, masks, w1f, whf, ws);
  hipLaunchKernelGGL(scan2, dim3(1), dim3(256), 0, stream, ws);
  hipLaunchKernelGGL(scan3, dim3(SCAN_BLOCKS), dim3(256), 0, stream,
                     rewards, masks, values, ws);
  hipLaunchKernelGGL(main3, dim3(T_TOTAL / 64), dim3(256), 0, stream,
                     states, actions, beta, b1, b_mu, b_lv, w1f, whf, ws);
  hipLaunchKernelGGL(finalize, dim3(1), dim3(64), 0, stream, ws, out);
}

// Round 7
// 446.479 us; speedup vs baseline: 1.0101x; 1.0101x over previous
//
#include <hip/hip_runtime.h>
#include <math.h>

// PPO fused loss, round 7 — proven components only, one delta.
//  aux  : round-4 split kernels (prep_scan1 / scan2 / scan3), verified absmax 0.0.
//  main2: round-3 kernel (pkbf packing, exp2-tanh, per-wave atomic), verified
//         absmax 0.0; SINGLE EDIT: wave_sync_lds -> __syncthreads (stronger
//         sync, removes the compiler scheduling fence that stalled r3).

typedef __attribute__((ext_vector_type(8))) short short8_t;
typedef __attribute__((ext_vector_type(4))) short short4_t;
typedef __attribute__((ext_vector_type(4))) float float4_t;
typedef __attribute__((ext_vector_type(2))) float float2_t;

#define T_TOTAL 262144
#define S_DIM 128
#define H_DIM 1024
#define A_DIM 16
#define GAMMA 0.99f

#define SEG 32
#define NSEG 8192
#define SCAN_BLOCKS 32

// ws float offsets
#define WS_SUM   0
#define WS_SUMSQ 1
#define WS_MEAN  2
#define WS_ISTD  3
#define WS_TERM  4
#define WS_CTR   5
#define WS_SEGA  8
#define WS_SEGB  (WS_SEGA + NSEG)
#define WS_INC   (WS_SEGB + NSEG)
#define WS_ADV   (WS_INC + NSEG)           // + T floats
#define WS_W1F   (WS_ADV + T_TOTAL)        // 131072 bf16
#define WS_WHF   (WS_W1F + 65536)          // 32768 bf16

// LDS layout (bytes) for main2
#define SM_A    0          // 16384 B : A1 fragments (64x128 bf16, frag order)
#define SM_H    16384      // 4 waves x 8704 B : per-wave h buf / C2 partials
#define SM_SIZE 51200

__device__ __forceinline__ unsigned pkbf(float a, float b) {
  unsigned r;
  asm("v_cvt_pk_bf16_f32 %0, %1, %2" : "=v"(r) : "v"(a), "v"(b));
  return r;
}

__device__ __forceinline__ float fast_tanh(float x) {
  float e = __builtin_amdgcn_exp2f(x * 2.8853900817779268f);
  return fmaf(-2.0f, __builtin_amdgcn_rcpf(e + 1.0f), 1.0f);
}

// ---------------- prep + scan1 (round-4, proven) ----------------
__global__ void prep_scan1(const float* __restrict__ W1,
                           const float* __restrict__ W_mu,
                           const float* __restrict__ W_lv,
                           const float* __restrict__ rewards,
                           const int* __restrict__ masks,
                           short* __restrict__ w1f, short* __restrict__ whf,
                           float* __restrict__ ws) {
  __shared__ float lr[8448], lg[8448];
  const int bid = blockIdx.x, tid = threadIdx.x;
  if (bid < 64) {
    int id = bid * 256 + tid;
    int lane = id & 63, kf = (id >> 6) & 3, nt = id >> 8;
    int quad = lane >> 4, col = nt * 16 + (lane & 15);
    int kbase = kf * 32 + quad * 8;
#pragma unroll
    for (int e = 0; e < 8; e += 2) {
      unsigned p = pkbf(W1[(size_t)(kbase + e) * H_DIM + col],
                        W1[(size_t)(kbase + e + 1) * H_DIM + col]);
      *(unsigned*)(w1f + (size_t)id * 8 + e) = p;
    }
  } else if (bid < 80) {
    if (bid == 64 && tid < 16) ws[tid] = 0.0f;
    int id = (bid - 64) * 256 + tid;
    int lane = id & 63, kf = (id >> 6) & 31, nt = id >> 11;
    const float* src = nt ? W_lv : W_mu;
    int quad = lane >> 4, col = lane & 15;
    int kbase = kf * 32 + quad * 8;
#pragma unroll
    for (int e = 0; e < 8; e += 2) {
      unsigned p = pkbf(src[(size_t)(kbase + e) * A_DIM + col],
                        src[(size_t)(kbase + e + 1) * A_DIM + col]);
      *(unsigned*)(whf + (size_t)id * 8 + e) = p;
    }
  } else {
    const int sb = bid - 80;
    const size_t base = (size_t)sb * 8192;
    const float4* r4 = (const float4*)(rewards + base);
    const int4* m4 = (const int4*)(masks + base);
#pragma unroll
    for (int i = 0; i < 8; ++i) {
      int idx4 = tid + i * 256;
      float4 rv = r4[idx4];
      int4 mv = m4[idx4];
      int j0 = idx4 * 4, p = j0 + (j0 >> 5);
      lr[p] = rv.x; lr[p + 1] = rv.y; lr[p + 2] = rv.z; lr[p + 3] = rv.w;
      lg[p] = GAMMA * (float)mv.x; lg[p + 1] = GAMMA * (float)mv.y;
      lg[p + 2] = GAMMA * (float)mv.z; lg[p + 3] = GAMMA * (float)mv.w;
    }
    __syncthreads();
    const float* pr = lr + 33 * tid;
    const float* pg = lg + 33 * tid;
    float a = 1.0f, b = 0.0f;
#pragma unroll
    for (int i = SEG - 1; i >= 0; --i) {
      float gi = pg[i];
      b = pr[i] + gi * b;
      a *= gi;
    }
    int g = sb * 256 + tid;
    ws[WS_SEGA + g] = a;
    ws[WS_SEGB + g] = b;
  }
}

// ---------------- scan pass 2 (round-4, proven) ----------------
__global__ void scan2(float* __restrict__ ws) {
  __shared__ float lA[8448], lB[8448];
  __shared__ float gA[256], gB[256], ginc[256];
  const int tid = threadIdx.x;
  const float4* a4 = (const float4*)(ws + WS_SEGA);
  const float4* b4 = (const float4*)(ws + WS_SEGB);
#pragma unroll
  for (int i = 0; i < 8; ++i) {
    int idx4 = tid + i * 256;
    float4 av = a4[idx4], bv = b4[idx4];
    int j0 = idx4 * 4, p = j0 + (j0 >> 5);
    lA[p] = av.x; lA[p + 1] = av.y; lA[p + 2] = av.z; lA[p + 3] = av.w;
    lB[p] = bv.x; lB[p + 1] = bv.y; lB[p + 2] = bv.z; lB[p + 3] = bv.w;
  }
  __syncthreads();
  {
    const float* pA = lA + 33 * tid;
    const float* pB = lB + 33 * tid;
    float A = 1.0f, B = 0.0f;
#pragma unroll
    for (int i = 31; i >= 0; --i) {
      float as = pA[i], bs = pB[i];
      B = bs + as * B;
      A = as * A;
    }
    gA[tid] = A; gB[tid] = B;
  }
  __syncthreads();
  if (tid == 0) {
    float x = 0.0f;
    for (int g = 255; g >= 0; --g) {
      ginc[g] = x;
      x = gB[g] + gA[g] * x;
    }
  }
  __syncthreads();
  {
    float x = ginc[tid];
    float* pA = lA + 33 * tid;
    const float* pB = lB + 33 * tid;
#pragma unroll
    for (int i = 31; i >= 0; --i) {
      float as = pA[i], bs = pB[i];
      pA[i] = x;
      x = bs + as * x;
    }
  }
  __syncthreads();
  float4* o4 = (float4*)(ws + WS_INC);
#pragma unroll
  for (int i = 0; i < 8; ++i) {
    int idx4 = tid + i * 256;
    int j0 = idx4 * 4, p = j0 + (j0 >> 5);
    o4[idx4] = make_float4(lA[p], lA[p + 1], lA[p + 2], lA[p + 3]);
  }
}

// ---------------- scan pass 3 + stats (round-4, proven) ----------------
__global__ void scan3(const float* __restrict__ rewards,
                      const int* __restrict__ masks,
                      const float* __restrict__ values,
                      float* __restrict__ ws) {
  __shared__ float lr[8448], lg[8448], lv[8448];
  const int tid = threadIdx.x;
  const size_t base = (size_t)blockIdx.x * 8192;
  const float4* r4 = (const float4*)(rewards + base);
  const int4* m4 = (const int4*)(masks + base);
  const float4* v4 = (const float4*)(values + base);
#pragma unroll
  for (int i = 0; i < 8; ++i) {
    int idx4 = tid + i * 256;
    float4 rv = r4[idx4];
    int4 mv = m4[idx4];
    float4 vv = v4[idx4];
    int j0 = idx4 * 4, p = j0 + (j0 >> 5);
    lr[p] = rv.x; lr[p + 1] = rv.y; lr[p + 2] = rv.z; lr[p + 3] = rv.w;
    lg[p] = GAMMA * (float)mv.x; lg[p + 1] = GAMMA * (float)mv.y;
    lg[p + 2] = GAMMA * (float)mv.z; lg[p + 3] = GAMMA * (float)mv.w;
    lv[p] = vv.x; lv[p + 1] = vv.y; lv[p + 2] = vv.z; lv[p + 3] = vv.w;
  }
  __syncthreads();
  float* pr = lr + 33 * tid;
  const float* pg = lg + 33 * tid;
  const float* pv = lv + 33 * tid;
  float x = ws[WS_INC + blockIdx.x * 256 + tid];
  float s1 = 0.0f, s2 = 0.0f;
#pragma unroll
  for (int i = SEG - 1; i >= 0; --i) {
    x = pr[i] + pg[i] * x;
    float adv = x - pv[i];
    pr[i] = adv;
    s1 += adv;
    s2 += adv * adv;
  }
#pragma unroll
  for (int m = 1; m < 64; m <<= 1) {
    s1 += __shfl_xor(s1, m);
    s2 += __shfl_xor(s2, m);
  }
  if ((tid & 63) == 0) {
    atomicAdd(&ws[WS_SUM], s1);
    atomicAdd(&ws[WS_SUMSQ], s2);
  }
  __syncthreads();
  float4* o4 = (float4*)(ws + WS_ADV + base);
#pragma unroll
  for (int i = 0; i < 8; ++i) {
    int idx4 = tid + i * 256;
    int j0 = idx4 * 4, p = j0 + (j0 >> 5);
    o4[idx4] = make_float4(lr[p], lr[p + 1], lr[p + 2], lr[p + 3]);
  }
  __threadfence();
  if (tid == 0) {
    int old = __hip_atomic_fetch_add((int*)ws + WS_CTR, 1,
                                     __ATOMIC_ACQ_REL, __HIP_MEMORY_SCOPE_AGENT);
    if (old == SCAN_BLOCKS - 1) {
      __threadfence();
      float t1 = __hip_atomic_load(&ws[WS_SUM], __ATOMIC_RELAXED, __HIP_MEMORY_SCOPE_AGENT);
      float t2 = __hip_atomic_load(&ws[WS_SUMSQ], __ATOMIC_RELAXED, __HIP_MEMORY_SCOPE_AGENT);
      float n = (float)T_TOTAL;
      float mean = t1 / n;
      float var = (t2 - t1 * t1 / n) / (n - 1.0f);
      var = fmaxf(var, 0.0f);
      ws[WS_MEAN] = mean;
      ws[WS_ISTD] = 1.0f / (sqrtf(var) + 1e-7f);
    }
  }
}

// ---------------- main GEMM + epilogue (round-3 kernel, barrier swap) ----------------
// 64 rows per block, 256 threads (4 waves). Wave w owns GEMM1 cols
// [w*256,(w+1)*256) == its GEMM2 K-range. K-loop sync: __syncthreads()
// (r2-proven scheduler-friendly), NOT inline-asm wave fences (r3 regression).
__launch_bounds__(256, 3)
__global__ void main2(const float* __restrict__ states,
                      const float* __restrict__ actions,
                      const float* __restrict__ beta,
                      const float* __restrict__ b1g,
                      const float* __restrict__ bmug,
                      const float* __restrict__ blvg,
                      const short* __restrict__ W1f,
                      const short* __restrict__ Whf,
                      float* __restrict__ ws) {
  __shared__ __align__(16) unsigned char smem[SM_SIZE];
  short* Ab = (short*)(smem + SM_A);

  const int tid = threadIdx.x;
  const int lane = tid & 63;
  const int w = tid >> 6;
  const int quad = lane >> 4;
  const int acol = lane & 15;
  const int t0 = blockIdx.x * 64;
  float* hw = (float*)(smem + SM_H) + w * 2176;   // 64 x 34 fp32, per-wave

  // ---- stage states (64x128 fp32) -> bf16 A1 fragments in LDS ----
  {
    const float4* src = (const float4*)(states + (size_t)t0 * S_DIM);
#pragma unroll
    for (int i = 0; i < 8; ++i) {
      int f = tid + i * 256;
      float4 v = src[f];
      int row = f >> 5, kq = f & 31;
      int rt = row >> 4, rr = row & 15;
      int k = kq * 4, kf = k >> 5, qd = (k >> 3) & 3, j0 = k & 7;
      union { unsigned u[2]; short4_t s; } pk;
      pk.u[0] = pkbf(v.x, v.y);
      pk.u[1] = pkbf(v.z, v.w);
      *(short4_t*)(Ab + (((rt * 4 + kf) * 64 + qd * 16 + rr) << 3) + j0) = pk.s;
    }
  }
  __syncthreads();

  // A1 fragments -> registers
  short8_t a1[4][4];
#pragma unroll
  for (int rt = 0; rt < 4; ++rt)
#pragma unroll
    for (int kf = 0; kf < 4; ++kf)
      a1[rt][kf] = *((const short8_t*)Ab + (rt * 4 + kf) * 64 + lane);

  float4_t acc2[4][2];
#pragma unroll
  for (int rt = 0; rt < 4; ++rt)
#pragma unroll
    for (int nt = 0; nt < 2; ++nt)
      acc2[rt][nt] = (float4_t){0.f, 0.f, 0.f, 0.f};

  const int nbase = w * 16;
  for (int kk = 0; kk < 8; ++kk) {
    // ---- GEMM1: two 16-col chunks -> tanh -> per-wave LDS h buf ----
#pragma unroll
    for (int c = 0; c < 2; ++c) {
      int nt1 = nbase + kk * 2 + c;
      const short8_t* bp = (const short8_t*)W1f + nt1 * 4 * 64 + lane;
      short8_t bf0 = bp[0], bf1 = bp[64], bf2 = bp[128], bf3 = bp[192];
      float b1v = b1g[nt1 * 16 + acol];
#pragma unroll
      for (int rt = 0; rt < 4; ++rt) {
        float4_t acc = (float4_t){0.f, 0.f, 0.f, 0.f};
        acc = __builtin_amdgcn_mfma_f32_16x16x32_bf16(a1[rt][0], bf0, acc, 0, 0, 0);
        acc = __builtin_amdgcn_mfma_f32_16x16x32_bf16(a1[rt][1], bf1, acc, 0, 0, 0);
        acc = __builtin_amdgcn_mfma_f32_16x16x32_bf16(a1[rt][2], bf2, acc, 0, 0, 0);
        acc = __builtin_amdgcn_mfma_f32_16x16x32_bf16(a1[rt][3], bf3, acc, 0, 0, 0);
        float* hp = hw + (rt * 16 + quad * 4) * 34 + c * 16 + acol;
        hp[0]   = fast_tanh(acc[0] + b1v);
        hp[34]  = fast_tanh(acc[1] + b1v);
        hp[68]  = fast_tanh(acc[2] + b1v);
        hp[102] = fast_tanh(acc[3] + b1v);
      }
    }
    __syncthreads();

    // ---- h chunk (64x32) -> A2 fragments (pk-cvt) -> GEMM2 ----
    int kf2 = w * 8 + kk;
    const short8_t* b2p = (const short8_t*)Whf + kf2 * 64 + lane;
    short8_t b2mu = b2p[0];
    short8_t b2lv = b2p[32 * 64];
#pragma unroll
    for (int rt = 0; rt < 4; ++rt) {
      const float* hp = hw + (rt * 16 + acol) * 34 + quad * 8;
      float2_t x0 = *(const float2_t*)hp;
      float2_t x1 = *(const float2_t*)(hp + 2);
      float2_t x2 = *(const float2_t*)(hp + 4);
      float2_t x3 = *(const float2_t*)(hp + 6);
      union { unsigned u[4]; short8_t s; } pk;
      pk.u[0] = pkbf(x0[0], x0[1]);
      pk.u[1] = pkbf(x1[0], x1[1]);
      pk.u[2] = pkbf(x2[0], x2[1]);
      pk.u[3] = pkbf(x3[0], x3[1]);
      acc2[rt][0] = __builtin_amdgcn_mfma_f32_16x16x32_bf16(pk.s, b2mu, acc2[rt][0], 0, 0, 0);
      acc2[rt][1] = __builtin_amdgcn_mfma_f32_16x16x32_bf16(pk.s, b2lv, acc2[rt][1], 0, 0, 0);
    }
    __syncthreads();   // WAR: next iter rewrites hw
  }

  // ---- cross-wave reduce of head partials (reuse own h region) ----
#pragma unroll
  for (int rt = 0; rt < 4; ++rt)
#pragma unroll
    for (int nt = 0; nt < 2; ++nt)
      *(float4_t*)(hw + ((rt * 2 + nt) * 64 + lane) * 4) = acc2[rt][nt];
  __syncthreads();

  // ---- epilogue ----
  const float mean = ws[WS_MEAN], istd = ws[WS_ISTD];
  const float* redbase = (const float*)(smem + SM_H);
  const int j = tid & 15;
  const int rsub = tid >> 4;
  float bmu = bmug[j], blv = blvg[j];
  float term = 0.0f;
#pragma unroll
  for (int p = 0; p < 4; ++p) {
    int m = p * 16 + rsub;
    int q2 = (m & 15) >> 2, reg = m & 3;
    float mu = bmu, lv = blv;
#pragma unroll
    for (int wv = 0; wv < 4; ++wv) {
      const float* rw = redbase + wv * 2176;
      mu += rw[((p * 2 + 0) * 64 + q2 * 16 + j) * 4 + reg];
      lv += rw[((p * 2 + 1) * 64 + q2 * 16 + j) * 4 + reg];
    }
    int t = t0 + m;
    float act = actions[(size_t)t * A_DIM + j];
    float blp = beta[(size_t)t * A_DIM + j];
    float isd = __expf(-0.5f * lv);
    float z = (act - mu) * isd;
    float d = -0.5f * z * z - 0.5f * lv - 0.9189385332046727f - blp;
    d += __shfl_xor(d, 1);
    d += __shfl_xor(d, 2);
    d += __shfl_xor(d, 4);
    d += __shfl_xor(d, 8);
    if (j == 0) {
      float ratio = __expf(d);
      float ah = (ws[WS_ADV + t] - mean) * istd;
      float rc = fminf(fmaxf(ratio, 0.8f), 1.2f);
      term += fminf(ratio * ah, rc * ah);
    }
  }
#pragma unroll
  for (int m2 = 1; m2 < 64; m2 <<= 1) term += __shfl_xor(term, m2);
  if (lane == 0) atomicAdd(&ws[WS_TERM], term);
}

__global__ void finalize(const float* __restrict__ ws, float* __restrict__ out) {
  if (threadIdx.x == 0) {
    float n = (float)T_TOTAL;
    out[0] = ws[WS_SUMSQ] / n - ws[WS_TERM] / n;
  }
}

extern "C" void kernel_launch(void* const* d_in, const int* in_sizes, int n_in,
                              void* d_out, int out_size, void* d_ws, size_t ws_size,
                              hipStream_t stream) {
  const float* states  = (const float*)d_in[0];
  const float* actions = (const float*)d_in[1];
  const float* rewards = (const float*)d_in[2];
  const float* values  = (const float*)d_in[3];
  const float* beta    = (const float*)d_in[4];
  const float* W1      = (const float*)d_in[5];
  const float* b1      = (const float*)d_in[6];
  const float* W_mu    = (const float*)d_in[7];
  const float* b_mu    = (const float*)d_in[8];
  const float* W_lv    = (const float*)d_in[9];
  const float* b_lv    = (const float*)d_in[10];
  const int*   masks   = (const int*)d_in[11];
  float* ws = (float*)d_ws;
  float* out = (float*)d_out;
  short* w1f = (short*)(ws + WS_W1F);
  short* whf = (short*)(ws + WS_WHF);

  hipLaunchKernelGGL(prep_scan1, dim3(112), dim3(256), 0, stream,
                     W1, W_mu, W_lv, rewards, masks, w1f, whf, ws);
  hipLaunchKernelGGL(scan2, dim3(1), dim3(256), 0, stream, ws);
  hipLaunchKernelGGL(scan3, dim3(SCAN_BLOCKS), dim3(256), 0, stream,
                     rewards, masks, values, ws);
  hipLaunchKernelGGL(main2, dim3(T_TOTAL / 64), dim3(256), 0, stream,
                     states, actions, beta, b1, b_mu, b_lv, w1f, whf, ws);
  hipLaunchKernelGGL(finalize, dim3(1), dim3(64), 0, stream, ws, out);
}